// Round 5
// baseline (460.067 us; speedup 1.0000x reference)
//
#include <hip/hip_runtime.h>
#include <math.h>

#define B_SZ 4
#define N_SEQ 2048
#define D_DIM 256
#define H_HEADS 4
#define E_DIM 256
#define ROWS (B_SZ*N_SEQ)
#define TOT_Q (H_HEADS*ROWS)
#define PAD_TOK -2.0f
#define LN_EPS 1e-6f

typedef __attribute__((ext_vector_type(8))) short short8;   // 8 x bf16 (4 VGPRs)
typedef __attribute__((ext_vector_type(4))) float f32x4;

static __device__ __forceinline__ unsigned short f2bf(float f){
  union { float f; unsigned u; } v; v.f = f;
  unsigned r = v.u + 0x7fffu + ((v.u >> 16) & 1u);
  return (unsigned short)(r >> 16);
}
static __device__ __forceinline__ float bf2f(unsigned short s){
  union { unsigned u; float f; } v; v.u = ((unsigned)s) << 16; return v.f;
}
static __device__ __forceinline__ f32x4 mfma16(short8 a, short8 b, f32x4 c){
  return __builtin_amdgcn_mfma_f32_16x16x32_bf16(a, b, c, 0, 0, 0);
}

#define GLOAD_LDS16(gsrc, ldst) \
  __builtin_amdgcn_global_load_lds((const __attribute__((address_space(1))) void*)(gsrc), \
                                   (__attribute__((address_space(3))) void*)(ldst), 16, 0, 0)

// ---------------- Kernel 1: input LN -> bf16 x_norm, mask value ----------------
__global__ __launch_bounds__(256) void k_ln_in(
    const float* __restrict__ x, const float* __restrict__ mask,
    const float* __restrict__ g, const float* __restrict__ bta,
    unsigned short* __restrict__ xn, float* __restrict__ mval){
  int row = blockIdx.x * 4 + (threadIdx.x >> 6);
  int lane = threadIdx.x & 63;
  const float* xr = x + (size_t)row * D_DIM + lane * 4;
  f32x4 v = *reinterpret_cast<const f32x4*>(xr);
  float s = v[0]+v[1]+v[2]+v[3];
  float q = v[0]*v[0]+v[1]*v[1]+v[2]*v[2]+v[3]*v[3];
  #pragma unroll
  for (int m=1;m<64;m<<=1){ s += __shfl_xor(s,m,64); q += __shfl_xor(q,m,64); }
  float mean = s * (1.0f/D_DIM);
  float var  = q * (1.0f/D_DIM) - mean*mean;
  float rs = rsqrtf(var + LN_EPS);
  int c = lane*4;
  ushort4 o;
  o.x = f2bf((v[0]-mean)*rs*g[c+0] + bta[c+0]);
  o.y = f2bf((v[1]-mean)*rs*g[c+1] + bta[c+1]);
  o.z = f2bf((v[2]-mean)*rs*g[c+2] + bta[c+2]);
  o.w = f2bf((v[3]-mean)*rs*g[c+3] + bta[c+3]);
  *reinterpret_cast<ushort4*>(xn + (size_t)row*D_DIM + c) = o;
  if (lane == 0) mval[row] = (mask[row] == PAD_TOK) ? 0.0f : 1.0f;
}

// ---------------- Kernel 2a: transpose QKVG weights -> wt[mat][e][d] bf16 ----------------
__global__ __launch_bounds__(256) void k_prep_w(
    const float* __restrict__ Wq, const float* __restrict__ Wk,
    const float* __restrict__ Wv, const float* __restrict__ Wg,
    unsigned short* __restrict__ wt){
  int mat = blockIdx.z; int proj = mat >> 2, h = mat & 3;
  const float* W = (proj==0 ? Wq : (proj==1 ? Wk : (proj==2 ? Wv : Wg))) + (size_t)h * D_DIM * E_DIM;
  __shared__ float tile[64][65];
  int e0 = blockIdx.x*64, d0 = blockIdx.y*64;
  #pragma unroll
  for (int i=0;i<16;i++){
    int idx = threadIdx.x + i*256;
    int dl = idx >> 6, el = idx & 63;
    tile[dl][el] = W[(size_t)(d0+dl)*E_DIM + e0 + el];
  }
  __syncthreads();
  #pragma unroll
  for (int i=0;i<16;i++){
    int idx = threadIdx.x + i*256;
    int el = idx >> 6, dl = idx & 63;
    wt[((size_t)mat*E_DIM + e0+el)*D_DIM + d0+dl] = f2bf(tile[dl][el]);
  }
}

// ------- Kernel 2b: out_w [e*H+h][col] -> owt[col][h*256+e] bf16 (B^T, perm baked) -------
__global__ __launch_bounds__(256) void k_prep_ow(
    const float* __restrict__ out_w, unsigned short* __restrict__ owt){
  int c0 = blockIdx.x*64;
  int col0 = blockIdx.y*64;
  int hh = c0 >> 8; int e0 = c0 & 255;
  __shared__ float tile[64][65];
  #pragma unroll
  for (int i=0;i<16;i++){
    int idx = threadIdx.x + i*256;
    int el = idx>>6, cl = idx&63;
    tile[el][cl] = out_w[(size_t)((e0+el)*H_HEADS + hh)*E_DIM + col0+cl];
  }
  __syncthreads();
  #pragma unroll
  for (int i=0;i<16;i++){
    int idx = threadIdx.x + i*256;
    int cl = idx>>6, el = idx&63;
    owt[(size_t)(col0+cl)*1024 + c0 + el] = f2bf(tile[el][cl]);
  }
}

// ------- Kernel 3: projections; 32 rows/wave; V transposed via LDS (coalesced) -------
__global__ __launch_bounds__(256,2) void k_proj(
    const unsigned short* __restrict__ xn, const unsigned short* __restrict__ wt,
    unsigned short* __restrict__ qb, unsigned short* __restrict__ kb,
    unsigned short* __restrict__ vtb, unsigned short* __restrict__ gpb){
  int mat = blockIdx.y; int proj = mat >> 2, h = mat & 3;
  int wv = threadIdx.x >> 6, lane = threadIdx.x & 63;
  int lr = lane & 15, lg = lane >> 4;
  int r0 = blockIdx.x * 128 + wv * 32;
  const unsigned short* wm = wt + (size_t)mat * D_DIM * E_DIM;
  __shared__ unsigned short vtile[16][136];
  short8 a[2][8];
  #pragma unroll
  for (int qr=0;qr<2;qr++){
    const unsigned short* arow = xn + (size_t)(r0 + qr*16 + lr) * D_DIM + lg*8;
    #pragma unroll
    for (int kk=0;kk<8;kk++) a[qr][kk] = *reinterpret_cast<const short8*>(arow + kk*32);
  }
  unsigned short* outp = (proj==0 ? qb : (proj==1 ? kb : gpb)) + (size_t)h * ROWS * E_DIM;
  int bb_ = (blockIdx.x*128) >> 11;
  int nbase = (blockIdx.x*128) & 2047;
  for (int nt=0; nt<16; nt++){
    f32x4 acc0 = f32x4{0.f,0.f,0.f,0.f};
    f32x4 acc1 = f32x4{0.f,0.f,0.f,0.f};
    const unsigned short* brow = wm + (size_t)(nt*16 + lr) * D_DIM + lg*8;
    #pragma unroll
    for (int kk=0;kk<8;kk++){
      short8 bfrag = *reinterpret_cast<const short8*>(brow + kk*32);
      acc0 = mfma16(a[0][kk], bfrag, acc0);
      acc1 = mfma16(a[1][kk], bfrag, acc1);
    }
    int col = nt*16 + lr;
    if (proj == 2){
      __syncthreads();
      #pragma unroll
      for (int r=0;r<4;r++){
        vtile[lr][wv*32 + lg*4 + r]      = f2bf(acc0[r]);
        vtile[lr][wv*32 + 16 + lg*4 + r] = f2bf(acc1[r]);
      }
      __syncthreads();
      int el = threadIdx.x >> 4, nl = (threadIdx.x & 15) * 8;
      short8 vv = *reinterpret_cast<const short8*>(&vtile[el][nl]);
      *reinterpret_cast<short8*>(
        vtb + ((size_t)(h*B_SZ + bb_)*E_DIM + nt*16 + el)*N_SEQ + nbase + nl) = vv;
    } else {
      #pragma unroll
      for (int r=0;r<4;r++){
        int row0 = r0 + lg*4 + r;
        outp[(size_t)row0*E_DIM + col] = f2bf(acc0[r]);
        outp[(size_t)(row0+16)*E_DIM + col] = f2bf(acc1[r]);
      }
    }
  }
}

// ---------------- Kernel 4: split-K flash attention (no-max softmax) ----------------
// grid 512: kh = id&1 (KV half), hb = (id>>1)&15, nblk = id>>5. 32 Q-rows/wave.
// KVBLK=64, single-buffered K/V via global_load_lds (swizzled), P in LDS [32][64] swizzled.
__global__ __launch_bounds__(256,2) void k_attn(
    const unsigned short* __restrict__ qb, const unsigned short* __restrict__ kb,
    const unsigned short* __restrict__ vt, const float* __restrict__ mval,
    unsigned short* __restrict__ po, float* __restrict__ lbuf){
  int id = blockIdx.x;
  int kh = id & 1;
  int hb = (id >> 1) & 15;
  int nblk = id >> 5;
  int h = hb >> 2, bbx = hb & 3;
  int tid = threadIdx.x;
  int wv = tid >> 6, lane = tid & 63;
  int lr = lane & 15, lg = lane >> 4;
  int n0 = nblk * 128 + wv * 32;
  const unsigned short* qm = qb + ((size_t)h * ROWS + (size_t)bbx * N_SEQ) * E_DIM;
  const unsigned short* km = kb + ((size_t)h * ROWS + (size_t)bbx * N_SEQ) * E_DIM;
  const char* vmb = (const char*)(vt + ((size_t)(h * B_SZ + bbx)) * E_DIM * N_SEQ);
  const float* mrow = mval + bbx * N_SEQ + kh * (N_SEQ/2);

  __shared__ alignas(16) unsigned short Klds[64*256];   // 32KB, row=512B, swz (n&7)<<4
  __shared__ alignas(16) unsigned short Vlds[256*64];   // 32KB, row=128B, swz (e&7)<<4
  __shared__ alignas(16) unsigned short Plds[4][32*64]; // 16KB, row=128B, swz (r&7)<<4

  short8 qf0[8], qf1[8];
  {
    const unsigned short* qr0 = qm + (size_t)(n0 + lr) * E_DIM + lg * 8;
    const unsigned short* qr1 = qm + (size_t)(n0 + 16 + lr) * E_DIM + lg * 8;
    #pragma unroll
    for (int kk=0;kk<8;kk++){
      qf0[kk] = *reinterpret_cast<const short8*>(qr0 + kk*32);
      qf1[kk] = *reinterpret_cast<const short8*>(qr1 + kk*32);
    }
  }
  f32x4 o0[16], o1[16];
  #pragma unroll
  for (int i=0;i<16;i++){ o0[i] = f32x4{0.f,0.f,0.f,0.f}; o1[i] = f32x4{0.f,0.f,0.f,0.f}; }
  float lp0[4] = {0.f,0.f,0.f,0.f}, lp1[4] = {0.f,0.f,0.f,0.f};
  char* pbase = (char*)(&Plds[wv][0]);
  unsigned swz = (unsigned)((lr&7)<<4);

  for (int it=0; it<16; it++){
    if (it) __syncthreads();   // prev tile fully consumed
    {
      const char* kgb = (const char*)(km + ((size_t)(kh*(N_SEQ/2) + it*64))*E_DIM);
      #pragma unroll
      for (int i=0;i<8;i++){
        int c = tid + i*256;
        int krow = c >> 5;
        unsigned off = ((unsigned)(c*16)) ^ ((unsigned)((krow&7)<<4));
        GLOAD_LDS16(kgb + off, (char*)Klds + c*16);
      }
      #pragma unroll
      for (int i=0;i<8;i++){
        int c = tid + i*256;
        int e = c >> 3;
        unsigned off = ((unsigned)((c&7)*16)) ^ ((unsigned)((e&7)<<4));
        GLOAD_LDS16(vmb + (size_t)e*(N_SEQ*2) + (size_t)(kh*16+it)*128 + off,
                    (char*)Vlds + c*16);
      }
    }
    __syncthreads();           // staged data visible
    // QK^T per 16-col tile + exp + P write (no max subtraction; sum deferred)
    #pragma unroll
    for (int ct=0; ct<4; ct++){
      f32x4 s0 = f32x4{0.f,0.f,0.f,0.f}, s1 = f32x4{0.f,0.f,0.f,0.f};
      const char* krow0 = (const char*)Klds + (ct*16+lr)*512;
      #pragma unroll
      for (int kk=0;kk<8;kk++){
        short8 b = *reinterpret_cast<const short8*>(krow0 + (((unsigned)(kk*64 + lg*16)) ^ swz));
        s0 = mfma16(qf0[kk], b, s0);
        s1 = mfma16(qf1[kk], b, s1);
      }
      float mk = (mrow[it*64 + ct*16 + lr] - 1.0f) * 1e9f;
      #pragma unroll
      for (int r=0;r<4;r++){
        float e0 = __expf(s0[r]*0.0625f + mk);
        float e1 = __expf(s1[r]*0.0625f + mk);
        lp0[r] += e0; lp1[r] += e1;
        int row0 = lg*4 + r, row1 = 16 + lg*4 + r;
        *(unsigned short*)(pbase + row0*128 + (((unsigned)(ct*32 + lr*2)) ^ ((unsigned)((row0&7)<<4)))) = f2bf(e0);
        *(unsigned short*)(pbase + row1*128 + (((unsigned)(ct*32 + lr*2)) ^ ((unsigned)((row1&7)<<4)))) = f2bf(e1);
      }
    }
    // PV: P A-frags (2 k-halves x 2 groups) x V B-frags
    short8 pa0a = *reinterpret_cast<const short8*>(pbase + lr*128      + (((unsigned)(lg*16)) ^ swz));
    short8 pa0b = *reinterpret_cast<const short8*>(pbase + lr*128      + (((unsigned)(64 + lg*16)) ^ swz));
    short8 pa1a = *reinterpret_cast<const short8*>(pbase + (16+lr)*128 + (((unsigned)(lg*16)) ^ swz));
    short8 pa1b = *reinterpret_cast<const short8*>(pbase + (16+lr)*128 + (((unsigned)(64 + lg*16)) ^ swz));
    #pragma unroll
    for (int et=0;et<16;et++){
      const char* vrow = (const char*)Vlds + (et*16+lr)*128;
      short8 bva = *reinterpret_cast<const short8*>(vrow + (((unsigned)(lg*16)) ^ swz));
      short8 bvb = *reinterpret_cast<const short8*>(vrow + (((unsigned)(64 + lg*16)) ^ swz));
      o0[et] = mfma16(pa0a, bva, o0[et]);
      o0[et] = mfma16(pa0b, bvb, o0[et]);
      o1[et] = mfma16(pa1a, bva, o1[et]);
      o1[et] = mfma16(pa1b, bvb, o1[et]);
    }
  }
  // epilogue: reduce l over the 16 k-lanes, write partials
  #pragma unroll
  for (int m=1;m<16;m<<=1){
    #pragma unroll
    for (int r=0;r<4;r++){ lp0[r] += __shfl_xor(lp0[r], m, 16); lp1[r] += __shfl_xor(lp1[r], m, 16); }
  }
  size_t rowbase = (size_t)kh*TOT_Q + (size_t)hb*N_SEQ + n0;
  if (lr == 0){
    #pragma unroll
    for (int r=0;r<4;r++){
      lbuf[rowbase + lg*4 + r]      = lp0[r];
      lbuf[rowbase + 16 + lg*4 + r] = lp1[r];
    }
  }
  #pragma unroll
  for (int et=0;et<16;et++){
    #pragma unroll
    for (int r=0;r<4;r++){
      po[(rowbase + lg*4 + r)*256 + et*16 + lr]      = f2bf(o0[et][r]);
      po[(rowbase + 16 + lg*4 + r)*256 + et*16 + lr] = f2bf(o1[et][r]);
    }
  }
}

// ------- Kernel 4b: combine halves + /l + gate + residual + LN -> attout bf16 -------
__global__ __launch_bounds__(256,2) void k_comb(
    const unsigned short* __restrict__ po, const float* __restrict__ lbuf,
    const unsigned short* __restrict__ gp, const float* __restrict__ x,
    const float* __restrict__ g_res, const float* __restrict__ b_res,
    unsigned short* __restrict__ attout){
  int bx = blockIdx.x;
  int hb = bx >> 5, sub = bx & 31;
  int h = hb >> 2, bbx = hb & 3;
  int t = threadIdx.x;
  int rl = t >> 2, qc = t & 3;       // 64 rows/block, 4 threads/row
  int n = sub*64 + rl;
  size_t grow = (size_t)hb*N_SEQ + n;
  float l = lbuf[grow] + lbuf[(size_t)TOT_Q + grow];
  float inv = (l > 0.f) ? 1.0f/l : 0.f;
  int c0 = qc*64;
  const unsigned short* p0 = po + grow*256 + c0;
  const unsigned short* p1 = po + ((size_t)TOT_Q)*256 + grow*256 + c0;
  const unsigned short* gr = gp + ((size_t)h*ROWS + (size_t)bbx*N_SEQ + n)*E_DIM + c0;
  const float* xr = x + ((size_t)(bbx*N_SEQ + n))*D_DIM + c0;
  float vals[64];
  float s1 = 0.f, s2 = 0.f;
  #pragma unroll
  for (int ch=0; ch<8; ch++){
    short8 a0 = *reinterpret_cast<const short8*>(p0 + ch*8);
    short8 a1 = *reinterpret_cast<const short8*>(p1 + ch*8);
    short8 gg = *reinterpret_cast<const short8*>(gr + ch*8);
    #pragma unroll
    for (int j=0;j<8;j++){
      float v = (bf2f((unsigned short)a0[j]) + bf2f((unsigned short)a1[j])) * inv;
      float gate = 1.0f/(1.0f + __expf(-bf2f((unsigned short)gg[j])));
      float val = v*gate + xr[ch*8+j];
      vals[ch*8+j] = val;
      s1 += val; s2 += val*val;
    }
  }
  s1 += __shfl_xor(s1,1,64); s2 += __shfl_xor(s2,1,64);
  s1 += __shfl_xor(s1,2,64); s2 += __shfl_xor(s2,2,64);
  float mean = s1*(1.0f/E_DIM);
  float var  = s2*(1.0f/E_DIM) - mean*mean;
  float rs = rsqrtf(var + LN_EPS);
  unsigned short* ob = attout + ((size_t)(bbx*N_SEQ + n))*1024 + h*256 + c0;
  #pragma unroll
  for (int ch=0; ch<8; ch++){
    short8 w;
    #pragma unroll
    for (int j=0;j<8;j++){
      int col = c0 + ch*8 + j;
      w[j] = (short)f2bf((vals[ch*8+j]-mean)*rs*g_res[col] + b_res[col]);
    }
    *reinterpret_cast<short8*>(ob + ch*8) = w;
  }
}

// ---------------- Kernel 5: out proj + bias + residual + LN + mask ----------------
__global__ __launch_bounds__(128) void k_final(
    const unsigned short* __restrict__ attout, const unsigned short* __restrict__ owt,
    const float* __restrict__ out_b, const float* __restrict__ x,
    const float* __restrict__ g_out, const float* __restrict__ b_out,
    const float* __restrict__ mval, float* __restrict__ out){
  int wv = threadIdx.x >> 6, lane = threadIdx.x & 63;
  int lr = lane & 15, lg = lane >> 4;
  int r0 = blockIdx.x * 32 + wv*16;
  f32x4 acc[16];
  #pragma unroll
  for (int i=0;i<16;i++) acc[i] = f32x4{0.f,0.f,0.f,0.f};
  const unsigned short* arow = attout + (size_t)(r0 + lr)*1024 + lg*8;
  for (int kg=0; kg<4; kg++){
    short8 a[8];
    #pragma unroll
    for (int kk=0;kk<8;kk++) a[kk] = *reinterpret_cast<const short8*>(arow + kg*256 + kk*32);
    #pragma unroll
    for (int nt=0;nt<16;nt++){
      const unsigned short* brow = owt + (size_t)(nt*16 + lr)*1024 + kg*256 + lg*8;
      #pragma unroll
      for (int kk=0;kk<8;kk++){
        short8 bfrag = *reinterpret_cast<const short8*>(brow + kk*32);
        acc[nt] = mfma16(a[kk], bfrag, acc[nt]);
      }
    }
  }
  float s1_[4]={0,0,0,0}, s2_[4]={0,0,0,0};
  #pragma unroll
  for (int nt=0;nt<16;nt++){
    int col = nt*16 + lr;
    float ob = out_b[col];
    #pragma unroll
    for (int r=0;r<4;r++){
      int row = r0 + lg*4 + r;
      float val = acc[nt][r] + ob + x[(size_t)row*D_DIM + col];
      acc[nt][r] = val;
      s1_[r]+=val; s2_[r]+=val*val;
    }
  }
  #pragma unroll
  for (int m=1;m<16;m<<=1){
    #pragma unroll
    for (int r=0;r<4;r++){ s1_[r]+=__shfl_xor(s1_[r],m,16); s2_[r]+=__shfl_xor(s2_[r],m,16); }
  }
  float mm_[4], rs_[4];
  #pragma unroll
  for (int r=0;r<4;r++){
    float mean = s1_[r]*(1.0f/E_DIM);
    float var  = s2_[r]*(1.0f/E_DIM) - mean*mean;
    mm_[r]=mean; rs_[r]=rsqrtf(var + LN_EPS);
  }
  #pragma unroll
  for (int nt=0;nt<16;nt++){
    int col = nt*16 + lr;
    float gg = g_out[col], bb2 = b_out[col];
    #pragma unroll
    for (int r=0;r<4;r++){
      int row = r0 + lg*4 + r;
      float y = ((acc[nt][r]-mm_[r])*rs_[r]*gg + bb2) * mval[row];
      out[(size_t)row*E_DIM + col] = y;
    }
  }
}

extern "C" void kernel_launch(void* const* d_in, const int* in_sizes, int n_in,
                              void* d_out, int out_size, void* d_ws, size_t ws_size,
                              hipStream_t stream) {
  const float* x     = (const float*)d_in[0];
  const float* mask  = (const float*)d_in[1];
  const float* Wq    = (const float*)d_in[2];
  const float* Wk    = (const float*)d_in[3];
  const float* Wv    = (const float*)d_in[4];
  const float* Wg    = (const float*)d_in[5];
  const float* out_w = (const float*)d_in[6];
  const float* out_b = (const float*)d_in[7];
  const float* g_in  = (const float*)d_in[8];
  const float* b_in  = (const float*)d_in[9];
  const float* g_res = (const float*)d_in[10];
  const float* b_res = (const float*)d_in[11];
  const float* g_out = (const float*)d_in[12];
  const float* b_out = (const float*)d_in[13];

  char* ws = (char*)d_ws;
  size_t off = 0;
  unsigned short* xn   = (unsigned short*)(ws + off); off += (size_t)ROWS * D_DIM * 2;           // 4 MB
  float*          mval = (float*)(ws + off);          off += (size_t)ROWS * 4;                   // 32 KB
  unsigned short* wt   = (unsigned short*)(ws + off); off += (size_t)16 * D_DIM * E_DIM * 2;     // 2 MB
  unsigned short* owt  = (unsigned short*)(ws + off); off += (size_t)E_DIM * 1024 * 2;           // 512 KB
  unsigned short* qb   = (unsigned short*)(ws + off); off += (size_t)H_HEADS * ROWS * E_DIM * 2; // 16 MB
  unsigned short* kb   = (unsigned short*)(ws + off); off += (size_t)H_HEADS * ROWS * E_DIM * 2; // 16 MB
  unsigned short* vtb  = (unsigned short*)(ws + off); off += (size_t)H_HEADS * ROWS * E_DIM * 2; // 16 MB
  unsigned short* gpb  = (unsigned short*)(ws + off); off += (size_t)H_HEADS * ROWS * E_DIM * 2; // 16 MB
  unsigned short* attout = (unsigned short*)(ws + off); off += (size_t)ROWS * 1024 * 2;          // 16 MB
  unsigned short* po   = (unsigned short*)(ws + off); off += (size_t)2 * TOT_Q * E_DIM * 2;      // 32 MB
  float*          lbuf = (float*)(ws + off);          off += (size_t)2 * TOT_Q * 4;              // 256 KB

  k_ln_in<<<dim3(ROWS/4), dim3(256), 0, stream>>>(x, mask, g_in, b_in, xn, mval);
  k_prep_w<<<dim3(4,4,16), dim3(256), 0, stream>>>(Wq, Wk, Wv, Wg, wt);
  k_prep_ow<<<dim3(16,4), dim3(256), 0, stream>>>(out_w, owt);
  k_proj<<<dim3(ROWS/128, 16), dim3(256), 0, stream>>>(xn, wt, qb, kb, vtb, gpb);
  k_attn<<<dim3(512), dim3(256), 0, stream>>>(qb, kb, vtb, mval, po, lbuf);
  k_comb<<<dim3(512), dim3(256), 0, stream>>>(po, lbuf, gpb, x, g_res, b_res, attout);
  k_final<<<dim3(ROWS/32), dim3(128), 0, stream>>>(attout, owt, out_b, x, g_out, b_out, mval, (float*)d_out);
}

// Round 6
// 367.217 us; speedup vs baseline: 1.2528x; 1.2528x over previous
//
#include <hip/hip_runtime.h>
#include <math.h>

#define B_SZ 4
#define N_SEQ 2048
#define D_DIM 256
#define H_HEADS 4
#define E_DIM 256
#define ROWS (B_SZ*N_SEQ)
#define TOT_Q (H_HEADS*ROWS)
#define PAD_TOK -2.0f
#define LN_EPS 1e-6f

typedef __attribute__((ext_vector_type(8))) short short8;   // 8 x bf16 (4 VGPRs)
typedef __attribute__((ext_vector_type(4))) float f32x4;

static __device__ __forceinline__ unsigned short f2bf(float f){
  union { float f; unsigned u; } v; v.f = f;
  unsigned r = v.u + 0x7fffu + ((v.u >> 16) & 1u);
  return (unsigned short)(r >> 16);
}
static __device__ __forceinline__ float bf2f(unsigned short s){
  union { unsigned u; float f; } v; v.u = ((unsigned)s) << 16; return v.f;
}
static __device__ __forceinline__ f32x4 mfma16(short8 a, short8 b, f32x4 c){
  return __builtin_amdgcn_mfma_f32_16x16x32_bf16(a, b, c, 0, 0, 0);
}

#define GLOAD_LDS16(gsrc, ldst) \
  __builtin_amdgcn_global_load_lds((const __attribute__((address_space(1))) void*)(gsrc), \
                                   (__attribute__((address_space(3))) void*)(ldst), 16, 0, 0)

// ---------------- Kernel 1: input LN -> bf16 x_norm, mask value ----------------
__global__ __launch_bounds__(256) void k_ln_in(
    const float* __restrict__ x, const float* __restrict__ mask,
    const float* __restrict__ g, const float* __restrict__ bta,
    unsigned short* __restrict__ xn, float* __restrict__ mval){
  int row = blockIdx.x * 4 + (threadIdx.x >> 6);
  int lane = threadIdx.x & 63;
  const float* xr = x + (size_t)row * D_DIM + lane * 4;
  f32x4 v = *reinterpret_cast<const f32x4*>(xr);
  float s = v[0]+v[1]+v[2]+v[3];
  float q = v[0]*v[0]+v[1]*v[1]+v[2]*v[2]+v[3]*v[3];
  #pragma unroll
  for (int m=1;m<64;m<<=1){ s += __shfl_xor(s,m,64); q += __shfl_xor(q,m,64); }
  float mean = s * (1.0f/D_DIM);
  float var  = q * (1.0f/D_DIM) - mean*mean;
  float rs = rsqrtf(var + LN_EPS);
  int c = lane*4;
  ushort4 o;
  o.x = f2bf((v[0]-mean)*rs*g[c+0] + bta[c+0]);
  o.y = f2bf((v[1]-mean)*rs*g[c+1] + bta[c+1]);
  o.z = f2bf((v[2]-mean)*rs*g[c+2] + bta[c+2]);
  o.w = f2bf((v[3]-mean)*rs*g[c+3] + bta[c+3]);
  *reinterpret_cast<ushort4*>(xn + (size_t)row*D_DIM + c) = o;
  if (lane == 0) mval[row] = (mask[row] == PAD_TOK) ? 0.0f : 1.0f;
}

// ---------------- Kernel 2a: transpose QKVG weights -> wt[mat][e][d] bf16 ----------------
__global__ __launch_bounds__(256) void k_prep_w(
    const float* __restrict__ Wq, const float* __restrict__ Wk,
    const float* __restrict__ Wv, const float* __restrict__ Wg,
    unsigned short* __restrict__ wt){
  int mat = blockIdx.z; int proj = mat >> 2, h = mat & 3;
  const float* W = (proj==0 ? Wq : (proj==1 ? Wk : (proj==2 ? Wv : Wg))) + (size_t)h * D_DIM * E_DIM;
  __shared__ float tile[64][65];
  int e0 = blockIdx.x*64, d0 = blockIdx.y*64;
  #pragma unroll
  for (int i=0;i<16;i++){
    int idx = threadIdx.x + i*256;
    int dl = idx >> 6, el = idx & 63;
    tile[dl][el] = W[(size_t)(d0+dl)*E_DIM + e0 + el];
  }
  __syncthreads();
  #pragma unroll
  for (int i=0;i<16;i++){
    int idx = threadIdx.x + i*256;
    int el = idx >> 6, dl = idx & 63;
    wt[((size_t)mat*E_DIM + e0+el)*D_DIM + d0+dl] = f2bf(tile[dl][el]);
  }
}

// ------- Kernel 2b: out_w [e*H+h][col] -> owt[col][h*256+e] bf16 (B^T, perm baked) -------
__global__ __launch_bounds__(256) void k_prep_ow(
    const float* __restrict__ out_w, unsigned short* __restrict__ owt){
  int c0 = blockIdx.x*64;
  int col0 = blockIdx.y*64;
  int hh = c0 >> 8; int e0 = c0 & 255;
  __shared__ float tile[64][65];
  #pragma unroll
  for (int i=0;i<16;i++){
    int idx = threadIdx.x + i*256;
    int el = idx>>6, cl = idx&63;
    tile[el][cl] = out_w[(size_t)((e0+el)*H_HEADS + hh)*E_DIM + col0+cl];
  }
  __syncthreads();
  #pragma unroll
  for (int i=0;i<16;i++){
    int idx = threadIdx.x + i*256;
    int cl = idx>>6, el = idx&63;
    owt[(size_t)(col0+cl)*1024 + c0 + el] = f2bf(tile[el][cl]);
  }
}

// ------- Kernel 3: projections; 64 rows/wave, 256 rows/block; V via LDS transpose -------
__global__ __launch_bounds__(256,1) void k_proj(
    const unsigned short* __restrict__ xn, const unsigned short* __restrict__ wt,
    unsigned short* __restrict__ qb, unsigned short* __restrict__ kb,
    unsigned short* __restrict__ vtb, unsigned short* __restrict__ gpb){
  int mat = blockIdx.y; int proj = mat >> 2, h = mat & 3;
  int wv = threadIdx.x >> 6, lane = threadIdx.x & 63;
  int lr = lane & 15, lg = lane >> 4;
  int r0 = blockIdx.x * 256 + wv * 64;
  const unsigned short* wm = wt + (size_t)mat * D_DIM * E_DIM;
  __shared__ unsigned short vtile[16][264];
  short8 a[4][8];
  #pragma unroll
  for (int qr=0;qr<4;qr++){
    const unsigned short* arow = xn + (size_t)(r0 + qr*16 + lr) * D_DIM + lg*8;
    #pragma unroll
    for (int kk=0;kk<8;kk++) a[qr][kk] = *reinterpret_cast<const short8*>(arow + kk*32);
  }
  unsigned short* outp = (proj==0 ? qb : (proj==1 ? kb : gpb)) + (size_t)h * ROWS * E_DIM;
  int bb_ = (blockIdx.x*256) >> 11;
  int nbase = (blockIdx.x*256) & 2047;
  for (int nt=0; nt<16; nt++){
    f32x4 acc[4];
    #pragma unroll
    for (int qr=0;qr<4;qr++) acc[qr] = f32x4{0.f,0.f,0.f,0.f};
    const unsigned short* brow = wm + (size_t)(nt*16 + lr) * D_DIM + lg*8;
    #pragma unroll
    for (int kk=0;kk<8;kk++){
      short8 bfrag = *reinterpret_cast<const short8*>(brow + kk*32);
      #pragma unroll
      for (int qr=0;qr<4;qr++) acc[qr] = mfma16(a[qr][kk], bfrag, acc[qr]);
    }
    int col = nt*16 + lr;
    if (proj == 2){
      __syncthreads();
      #pragma unroll
      for (int qr=0;qr<4;qr++){
        #pragma unroll
        for (int r=0;r<4;r++)
          vtile[lr][wv*64 + qr*16 + lg*4 + r] = f2bf(acc[qr][r]);
      }
      __syncthreads();
      int el = threadIdx.x >> 4, nl0 = (threadIdx.x & 15) * 16;
      short8 v0 = *reinterpret_cast<const short8*>(&vtile[el][nl0]);
      short8 v1 = *reinterpret_cast<const short8*>(&vtile[el][nl0+8]);
      unsigned short* dst = vtb + ((size_t)(h*B_SZ + bb_)*E_DIM + nt*16 + el)*N_SEQ + nbase + nl0;
      *reinterpret_cast<short8*>(dst) = v0;
      *reinterpret_cast<short8*>(dst+8) = v1;
    } else {
      #pragma unroll
      for (int qr=0;qr<4;qr++){
        #pragma unroll
        for (int r=0;r<4;r++)
          outp[(size_t)(r0 + qr*16 + lg*4 + r)*E_DIM + col] = f2bf(acc[qr][r]);
      }
    }
  }
}

// ---------------- Kernel 4: split-K flash attention (no-max softmax) ----------------
// grid 512: kh = id&1, hb = (id>>1)&15 (combo on one XCD), nblk = id>>5. 32 Q-rows/wave.
// KVBLK=64 via global_load_lds (swizzled); coalesced po epilogue via LDS scratch.
__global__ __launch_bounds__(256,1) void k_attn(
    const unsigned short* __restrict__ qb, const unsigned short* __restrict__ kb,
    const unsigned short* __restrict__ vt, const float* __restrict__ mval,
    unsigned short* __restrict__ po, float* __restrict__ lbuf){
  int id = blockIdx.x;
  int kh = id & 1;
  int hb = (id >> 1) & 15;
  int nblk = id >> 5;
  int h = hb >> 2, bbx = hb & 3;
  int tid = threadIdx.x;
  int wv = tid >> 6, lane = tid & 63;
  int lr = lane & 15, lg = lane >> 4;
  int n0 = nblk * 128 + wv * 32;
  const unsigned short* qm = qb + ((size_t)h * ROWS + (size_t)bbx * N_SEQ) * E_DIM;
  const unsigned short* km = kb + ((size_t)h * ROWS + (size_t)bbx * N_SEQ) * E_DIM;
  const char* vmb = (const char*)(vt + ((size_t)(h * B_SZ + bbx)) * E_DIM * N_SEQ);
  const float* mrow = mval + bbx * N_SEQ + kh * (N_SEQ/2);

  __shared__ alignas(16) char smem[81920];
  char* Kb = smem;                       // 32 KB: 64 x 512B rows, swz (n&7)<<4
  char* Vb = smem + 32768;               // 32 KB: 256 x 128B rows, swz (e&7)<<4
  char* pbase = smem + 65536 + wv*4096;  // 16 KB: per-wave P [32][128B], swz (r&7)<<4

  short8 qf0[8], qf1[8];
  {
    const unsigned short* qr0 = qm + (size_t)(n0 + lr) * E_DIM + lg * 8;
    const unsigned short* qr1 = qm + (size_t)(n0 + 16 + lr) * E_DIM + lg * 8;
    #pragma unroll
    for (int kk=0;kk<8;kk++){
      qf0[kk] = *reinterpret_cast<const short8*>(qr0 + kk*32);
      qf1[kk] = *reinterpret_cast<const short8*>(qr1 + kk*32);
    }
  }
  f32x4 o0[16], o1[16];
  #pragma unroll
  for (int i=0;i<16;i++){ o0[i] = f32x4{0.f,0.f,0.f,0.f}; o1[i] = f32x4{0.f,0.f,0.f,0.f}; }
  float lp0[4] = {0.f,0.f,0.f,0.f}, lp1[4] = {0.f,0.f,0.f,0.f};
  unsigned swz = (unsigned)((lr&7)<<4);

  for (int it=0; it<16; it++){
    if (it) __syncthreads();   // prev tile fully consumed
    {
      const char* kgb = (const char*)(km + ((size_t)(kh*(N_SEQ/2) + it*64))*E_DIM);
      #pragma unroll
      for (int i=0;i<8;i++){
        int c = tid + i*256;
        int krow = c >> 5;
        unsigned off = ((unsigned)(c*16)) ^ ((unsigned)((krow&7)<<4));
        GLOAD_LDS16(kgb + off, Kb + c*16);
      }
      #pragma unroll
      for (int i=0;i<8;i++){
        int c = tid + i*256;
        int e = c >> 3;
        unsigned off = ((unsigned)((c&7)*16)) ^ ((unsigned)((e&7)<<4));
        GLOAD_LDS16(vmb + (size_t)e*(N_SEQ*2) + (size_t)(kh*16+it)*128 + off,
                    Vb + c*16);
      }
    }
    __syncthreads();           // staged data visible
    // QK^T per 16-col tile + exp + P write (no max; sum deferred to epilogue)
    #pragma unroll
    for (int ct=0; ct<4; ct++){
      f32x4 s0 = f32x4{0.f,0.f,0.f,0.f}, s1 = f32x4{0.f,0.f,0.f,0.f};
      const char* krow0 = Kb + (ct*16+lr)*512;
      #pragma unroll
      for (int kk=0;kk<8;kk++){
        short8 b = *reinterpret_cast<const short8*>(krow0 + (((unsigned)(kk*64 + lg*16)) ^ swz));
        s0 = mfma16(qf0[kk], b, s0);
        s1 = mfma16(qf1[kk], b, s1);
      }
      float mk = (mrow[it*64 + ct*16 + lr] - 1.0f) * 1e9f;
      #pragma unroll
      for (int r=0;r<4;r++){
        float e0 = __expf(s0[r]*0.0625f + mk);
        float e1 = __expf(s1[r]*0.0625f + mk);
        lp0[r] += e0; lp1[r] += e1;
        int row0 = lg*4 + r, row1 = 16 + lg*4 + r;
        *(unsigned short*)(pbase + row0*128 + (((unsigned)(ct*32 + lr*2)) ^ ((unsigned)((row0&7)<<4)))) = f2bf(e0);
        *(unsigned short*)(pbase + row1*128 + (((unsigned)(ct*32 + lr*2)) ^ ((unsigned)((row1&7)<<4)))) = f2bf(e1);
      }
    }
    // PV
    short8 pa0a = *reinterpret_cast<const short8*>(pbase + lr*128      + (((unsigned)(lg*16)) ^ swz));
    short8 pa0b = *reinterpret_cast<const short8*>(pbase + lr*128      + (((unsigned)(64 + lg*16)) ^ swz));
    short8 pa1a = *reinterpret_cast<const short8*>(pbase + (16+lr)*128 + (((unsigned)(lg*16)) ^ swz));
    short8 pa1b = *reinterpret_cast<const short8*>(pbase + (16+lr)*128 + (((unsigned)(64 + lg*16)) ^ swz));
    #pragma unroll
    for (int et=0;et<16;et++){
      const char* vrow = Vb + (et*16+lr)*128;
      short8 bva = *reinterpret_cast<const short8*>(vrow + (((unsigned)(lg*16)) ^ swz));
      short8 bvb = *reinterpret_cast<const short8*>(vrow + (((unsigned)(64 + lg*16)) ^ swz));
      o0[et] = mfma16(pa0a, bva, o0[et]);
      o0[et] = mfma16(pa0b, bvb, o0[et]);
      o1[et] = mfma16(pa1a, bva, o1[et]);
      o1[et] = mfma16(pa1b, bvb, o1[et]);
    }
  }
  // ---- epilogue ----
  #pragma unroll
  for (int m=1;m<16;m<<=1){
    #pragma unroll
    for (int r=0;r<4;r++){ lp0[r] += __shfl_xor(lp0[r], m, 16); lp1[r] += __shfl_xor(lp1[r], m, 16); }
  }
  size_t rowbase = (size_t)kh*TOT_Q + (size_t)hb*N_SEQ + n0;
  if (lr == 0){
    #pragma unroll
    for (int r=0;r<4;r++){
      lbuf[rowbase + lg*4 + r]      = lp0[r];
      lbuf[rowbase + 16 + lg*4 + r] = lp1[r];
    }
  }
  __syncthreads();             // all compute done; K/V LDS reusable as scratch
  char* tb = smem + wv*16384;  // 16 KB per wave: [32 rows][512 B]
  #pragma unroll
  for (int et=0;et<16;et++){
    #pragma unroll
    for (int r=0;r<4;r++){
      int c2 = (et*16 + lr)*2;
      *(unsigned short*)(tb + (lg*4+r)*512 + c2)      = f2bf(o0[et][r]);
      *(unsigned short*)(tb + (16+lg*4+r)*512 + c2)   = f2bf(o1[et][r]);
    }
  }
  #pragma unroll
  for (int w=0; w<16; w++){
    int c = lane + w*64;       // linear: 64 lanes read 1024B contiguous
    short8 v = *reinterpret_cast<const short8*>(tb + c*16);
    int row = c >> 5, cc = (c & 31)*8;
    *reinterpret_cast<short8*>(po + (rowbase + row)*256 + cc) = v;
  }
}

// ------- Kernel 4b: combine halves + /l + gate + residual + LN -> attout bf16 -------
__global__ __launch_bounds__(256,2) void k_comb(
    const unsigned short* __restrict__ po, const float* __restrict__ lbuf,
    const unsigned short* __restrict__ gp, const float* __restrict__ x,
    const float* __restrict__ g_res, const float* __restrict__ b_res,
    unsigned short* __restrict__ attout){
  int bx = blockIdx.x;
  int hb = bx >> 5, sub = bx & 31;
  int h = hb >> 2, bbx = hb & 3;
  int t = threadIdx.x;
  int rl = t >> 2, qc = t & 3;
  int n = sub*64 + rl;
  size_t grow = (size_t)hb*N_SEQ + n;
  float l = lbuf[grow] + lbuf[(size_t)TOT_Q + grow];
  float inv = (l > 0.f) ? 1.0f/l : 0.f;
  int c0 = qc*64;
  const unsigned short* p0 = po + grow*256 + c0;
  const unsigned short* p1 = po + ((size_t)TOT_Q)*256 + grow*256 + c0;
  const unsigned short* gr = gp + ((size_t)h*ROWS + (size_t)bbx*N_SEQ + n)*E_DIM + c0;
  const float* xr = x + ((size_t)(bbx*N_SEQ + n))*D_DIM + c0;
  float vals[64];
  float s1 = 0.f, s2 = 0.f;
  #pragma unroll
  for (int ch=0; ch<8; ch++){
    short8 a0 = *reinterpret_cast<const short8*>(p0 + ch*8);
    short8 a1 = *reinterpret_cast<const short8*>(p1 + ch*8);
    short8 gg = *reinterpret_cast<const short8*>(gr + ch*8);
    #pragma unroll
    for (int j=0;j<8;j++){
      float v = (bf2f((unsigned short)a0[j]) + bf2f((unsigned short)a1[j])) * inv;
      float gate = 1.0f/(1.0f + __expf(-bf2f((unsigned short)gg[j])));
      float val = v*gate + xr[ch*8+j];
      vals[ch*8+j] = val;
      s1 += val; s2 += val*val;
    }
  }
  s1 += __shfl_xor(s1,1,64); s2 += __shfl_xor(s2,1,64);
  s1 += __shfl_xor(s1,2,64); s2 += __shfl_xor(s2,2,64);
  float mean = s1*(1.0f/E_DIM);
  float var  = s2*(1.0f/E_DIM) - mean*mean;
  float rs = rsqrtf(var + LN_EPS);
  unsigned short* ob = attout + ((size_t)(bbx*N_SEQ + n))*1024 + h*256 + c0;
  #pragma unroll
  for (int ch=0; ch<8; ch++){
    short8 w;
    #pragma unroll
    for (int j=0;j<8;j++){
      int col = c0 + ch*8 + j;
      w[j] = (short)f2bf((vals[ch*8+j]-mean)*rs*g_res[col] + b_res[col]);
    }
    *reinterpret_cast<short8*>(ob + ch*8) = w;
  }
}

// ---------------- Kernel 5: out proj + bias + residual + LN + mask ----------------
__global__ __launch_bounds__(128) void k_final(
    const unsigned short* __restrict__ attout, const unsigned short* __restrict__ owt,
    const float* __restrict__ out_b, const float* __restrict__ x,
    const float* __restrict__ g_out, const float* __restrict__ b_out,
    const float* __restrict__ mval, float* __restrict__ out){
  int wv = threadIdx.x >> 6, lane = threadIdx.x & 63;
  int lr = lane & 15, lg = lane >> 4;
  int r0 = blockIdx.x * 32 + wv*16;
  f32x4 acc[16];
  #pragma unroll
  for (int i=0;i<16;i++) acc[i] = f32x4{0.f,0.f,0.f,0.f};
  const unsigned short* arow = attout + (size_t)(r0 + lr)*1024 + lg*8;
  for (int kg=0; kg<4; kg++){
    short8 a[8];
    #pragma unroll
    for (int kk=0;kk<8;kk++) a[kk] = *reinterpret_cast<const short8*>(arow + kg*256 + kk*32);
    #pragma unroll
    for (int nt=0;nt<16;nt++){
      const unsigned short* brow = owt + (size_t)(nt*16 + lr)*1024 + kg*256 + lg*8;
      #pragma unroll
      for (int kk=0;kk<8;kk++){
        short8 bfrag = *reinterpret_cast<const short8*>(brow + kk*32);
        acc[nt] = mfma16(a[kk], bfrag, acc[nt]);
      }
    }
  }
  float s1_[4]={0,0,0,0}, s2_[4]={0,0,0,0};
  #pragma unroll
  for (int nt=0;nt<16;nt++){
    int col = nt*16 + lr;
    float ob = out_b[col];
    #pragma unroll
    for (int r=0;r<4;r++){
      int row = r0 + lg*4 + r;
      float val = acc[nt][r] + ob + x[(size_t)row*D_DIM + col];
      acc[nt][r] = val;
      s1_[r]+=val; s2_[r]+=val*val;
    }
  }
  #pragma unroll
  for (int m=1;m<16;m<<=1){
    #pragma unroll
    for (int r=0;r<4;r++){ s1_[r]+=__shfl_xor(s1_[r],m,16); s2_[r]+=__shfl_xor(s2_[r],m,16); }
  }
  float mm_[4], rs_[4];
  #pragma unroll
  for (int r=0;r<4;r++){
    float mean = s1_[r]*(1.0f/E_DIM);
    float var  = s2_[r]*(1.0f/E_DIM) - mean*mean;
    mm_[r]=mean; rs_[r]=rsqrtf(var + LN_EPS);
  }
  #pragma unroll
  for (int nt=0;nt<16;nt++){
    int col = nt*16 + lr;
    float gg = g_out[col], bb2 = b_out[col];
    #pragma unroll
    for (int r=0;r<4;r++){
      int row = r0 + lg*4 + r;
      float y = ((acc[nt][r]-mm_[r])*rs_[r]*gg + bb2) * mval[row];
      out[(size_t)row*E_DIM + col] = y;
    }
  }
}

extern "C" void kernel_launch(void* const* d_in, const int* in_sizes, int n_in,
                              void* d_out, int out_size, void* d_ws, size_t ws_size,
                              hipStream_t stream) {
  const float* x     = (const float*)d_in[0];
  const float* mask  = (const float*)d_in[1];
  const float* Wq    = (const float*)d_in[2];
  const float* Wk    = (const float*)d_in[3];
  const float* Wv    = (const float*)d_in[4];
  const float* Wg    = (const float*)d_in[5];
  const float* out_w = (const float*)d_in[6];
  const float* out_b = (const float*)d_in[7];
  const float* g_in  = (const float*)d_in[8];
  const float* b_in  = (const float*)d_in[9];
  const float* g_res = (const float*)d_in[10];
  const float* b_res = (const float*)d_in[11];
  const float* g_out = (const float*)d_in[12];
  const float* b_out = (const float*)d_in[13];

  char* ws = (char*)d_ws;
  size_t off = 0;
  unsigned short* xn   = (unsigned short*)(ws + off); off += (size_t)ROWS * D_DIM * 2;           // 4 MB
  float*          mval = (float*)(ws + off);          off += (size_t)ROWS * 4;                   // 32 KB
  unsigned short* wt   = (unsigned short*)(ws + off); off += (size_t)16 * D_DIM * E_DIM * 2;     // 2 MB
  unsigned short* owt  = (unsigned short*)(ws + off); off += (size_t)E_DIM * 1024 * 2;           // 512 KB
  unsigned short* qb   = (unsigned short*)(ws + off); off += (size_t)H_HEADS * ROWS * E_DIM * 2; // 16 MB
  unsigned short* kb   = (unsigned short*)(ws + off); off += (size_t)H_HEADS * ROWS * E_DIM * 2; // 16 MB
  unsigned short* vtb  = (unsigned short*)(ws + off); off += (size_t)H_HEADS * ROWS * E_DIM * 2; // 16 MB
  unsigned short* gpb  = (unsigned short*)(ws + off); off += (size_t)H_HEADS * ROWS * E_DIM * 2; // 16 MB
  unsigned short* attout = (unsigned short*)(ws + off); off += (size_t)ROWS * 1024 * 2;          // 16 MB
  unsigned short* po   = (unsigned short*)(ws + off); off += (size_t)2 * TOT_Q * E_DIM * 2;      // 32 MB
  float*          lbuf = (float*)(ws + off);          off += (size_t)2 * TOT_Q * 4;              // 256 KB

  k_ln_in<<<dim3(ROWS/4), dim3(256), 0, stream>>>(x, mask, g_in, b_in, xn, mval);
  k_prep_w<<<dim3(4,4,16), dim3(256), 0, stream>>>(Wq, Wk, Wv, Wg, wt);
  k_prep_ow<<<dim3(16,4), dim3(256), 0, stream>>>(out_w, owt);
  k_proj<<<dim3(ROWS/256, 16), dim3(256), 0, stream>>>(xn, wt, qb, kb, vtb, gpb);
  k_attn<<<dim3(512), dim3(256), 0, stream>>>(qb, kb, vtb, mval, po, lbuf);
  k_comb<<<dim3(512), dim3(256), 0, stream>>>(po, lbuf, gpb, x, g_res, b_res, attout);
  k_final<<<dim3(ROWS/32), dim3(128), 0, stream>>>(attout, owt, out_b, x, g_out, b_out, mval, (float*)d_out);
}